// Round 8
// baseline (288.983 us; speedup 1.0000x reference)
//
#include <hip/hip_runtime.h>
#include <hip/hip_bf16.h>

#define NBATCH 8
#define NP     4096
#define ND     61
#define NK     16
#define BN     (NBATCH*NP)

// ws layout (bytes)
#define OFF_XYZT  0                          // float4 * BN       = 524288
#define OFF_IDX   (OFF_XYZT + BN*16)         // int * BN*16       = 2097152
#define OFF_PTST  (OFF_IDX + BN*64)          // float * BN*64     = 8388608
#define OFF_BFRAG (OFF_PTST + BN*256)        // uint4 * 8192      = 131072
// total < 11272192 bytes (same budget as R2-R7 — known safe)

typedef __attribute__((ext_vector_type(8))) short bf16x8;
typedef __attribute__((ext_vector_type(4))) float f32x4;

static __device__ __forceinline__ unsigned short f2bf(float x) {
    unsigned int u = __float_as_uint(x);
    return (unsigned short)((u + 0x7fffu + ((u >> 16) & 1u)) >> 16);   // RNE
}

__global__ __launch_bounds__(256) void k_prep_xyz(const float* __restrict__ xyz,
                                                  float4* __restrict__ xyzt) {
#pragma clang fp contract(off)
    int t = blockIdx.x * 256 + threadIdx.x;      // 0..BN-1
    int b = t >> 12, n = t & (NP - 1);
    const float* base = xyz + (size_t)b * 3 * NP + n;
    float x = base[0], y = base[NP], z = base[2 * NP];
    // match numpy: sum(xyz*xyz, -1) = ((x*x + y*y) + z*z), no FMA fusion
    float sq = ((x * x) + (y * y)) + (z * z);
    xyzt[t] = make_float4(x, y, z, sq);
}

__global__ __launch_bounds__(256) void k_prep_ptst(const float* __restrict__ pts,
                                                   float* __restrict__ ptst) {
    __shared__ float tile[64][65];
    int blk = blockIdx.x;                 // NBATCH * (NP/64) = 512
    int b = blk >> 6; int n0 = (blk & 63) << 6;
    int tid = threadIdx.x; int rg = tid >> 6; int cl = tid & 63;
#pragma unroll
    for (int d0 = 0; d0 < 64; d0 += 4) {
        int d = d0 + rg;
        if (d < ND) tile[d][cl] = pts[((size_t)b * ND + d) * NP + n0 + cl];
    }
    __syncthreads();
#pragma unroll
    for (int r = 0; r < 16; ++r) {
        int n1 = r * 4 + rg;
        float v = (cl < ND) ? tile[cl][n1] : 0.0f;
        ptst[((size_t)b * NP + n0 + n1) * 64 + cl] = v;
    }
}

// B fragments for mfma_f32_16x16x32_bf16: B[k][n] = lin_w[n][k].
__global__ __launch_bounds__(256) void k_prep_bfrag(const float* __restrict__ lw,
                                                    uint4* __restrict__ bfrag) {
    int e = blockIdx.x * 256 + threadIdx.x;   // 32 blocks -> 8192 threads
    int lane = e & 63, nt = (e >> 6) & 3, ks = e >> 8;
    int k0 = ks * 32 + (lane >> 4) * 8;
    int n = nt * 16 + (lane & 15);
    const float* src = lw + (size_t)n * 1024 + k0;
    unsigned int pk[4];
#pragma unroll
    for (int i = 0; i < 4; ++i)
        pk[i] = ((unsigned int)f2bf(src[2 * i + 1]) << 16) | f2bf(src[2 * i]);
    bfrag[e] = make_uint4(pk[0], pk[1], pk[2], pk[3]);
}

#define INSERT16(dv, jv)                                            \
    do {                                                            \
        bd[15] = (dv); bi[15] = (jv);                               \
        _Pragma("unroll")                                           \
        for (int s_ = 15; s_ > 0; --s_) {                           \
            bool sw_ = bd[s_] < bd[s_ - 1];                         \
            float td_ = bd[s_]; int ti_ = bi[s_];                   \
            bd[s_]     = sw_ ? bd[s_ - 1] : td_;                    \
            bi[s_]     = sw_ ? bi[s_ - 1] : ti_;                    \
            bd[s_ - 1] = sw_ ? td_ : bd[s_ - 1];                    \
            bi[s_ - 1] = sw_ ? ti_ : bi[s_ - 1];                    \
        }                                                           \
    } while (0)

// Drain the u16-idx ring: re-fetch candidate via global gather (L2-resident),
// recompute EXACT (numpy op-order) distance via _rn intrinsics, strict-<
// check, insert. Slot loop ROLLED (small I$); INSERT16 unrolled.
#define DRAIN16()                                                             \
    do {                                                                      \
        for (int r_ = 0; r_ < 16; ++r_) {                                     \
            if (!__any(r_ < cnt)) break;                                      \
            if (r_ < cnt) {                                                   \
                int loc_ = ring[r_ * 64 + lane];                              \
                float4 cd_ = xb[cbase + loc_];                                \
                float dot_ = __fadd_rn(__fadd_rn(__fmul_rn(cd_.x, me.x),      \
                                                 __fmul_rn(cd_.y, me.y)),     \
                                       __fmul_rn(cd_.z, me.z));               \
                float dist_ = __fsub_rn(__fadd_rn(me.w, cd_.w),               \
                                        __fmul_rn(2.0f, dot_));               \
                if (dist_ < bd[15]) {                                         \
                    int gj_ = cbase + loc_;                                   \
                    INSERT16(dist_, gj_);                                     \
                }                                                             \
            }                                                                 \
        }                                                                     \
        cnt = 0;                                                              \
        T = fminf(T, (bd[15] - me.w) + 1.0e-3f);                              \
    } while (0)

// share thresholds across the 8 waves (all serve the same 64 queries):
// T can only tighten toward (global d16 + margin); stale reads are looser->safe
#define TSYNC()                                                               \
    do {                                                                      \
        Tsh[w * 64 + lane] = bd[15];                                          \
        float tm_ = Tsh[lane];                                                \
        _Pragma("unroll")                                                     \
        for (int v_ = 1; v_ < 8; ++v_) tm_ = fminf(tm_, Tsh[v_ * 64 + lane]); \
        T = fminf(T, (tm_ - me.w) + 1.0e-3f);                                 \
    } while (0)

// 8 waves per block; wave w scans candidate range [w*512, w*512+512) for the
// block's 64 queries (lane=query); two-stage ordered in-block merge.
// 34KB LDS -> 4 blocks/CU (32 waves/CU); VGPR pinned <=64 via launch_bounds.
__global__ __launch_bounds__(512, 8) void k_knn(const float4* __restrict__ xyzt,
                                                int* __restrict__ out) {
    __shared__ char smem[34816];
    int tid = threadIdx.x;
    int w = __builtin_amdgcn_readfirstlane(tid >> 6);   // wave id, SGPR-uniform
    int lane = tid & 63;
    int blk = blockIdx.x;               // 512 blocks
    int b = blk >> 6;
    int qbase = (blk & 63) << 6;
    const float4* xb = xyzt + (size_t)b * NP;

    unsigned short* ring = (unsigned short*)(smem + w * 2048);  // [16][64] u16
    float* Tsh = (float*)(smem + 32768);                        // [8][64]
    float2* part = (float2*)smem;       // [4][16][64] float2 = 32KB merge overlay

    float4 me = xb[qbase + lane];
    float bd[16]; int bi[16];
#pragma unroll
    for (int i = 0; i < 16; ++i) { bd[i] = 3.0e38f; bi[i] = 0; }
    int cnt = 0;
    float T = 3.0e38f;                  // filter threshold (on df = dist - me.w)
    Tsh[w * 64 + lane] = 3.0e38f;
    __syncthreads();                    // Tsh init visible before any TSYNC read

    int cbase = w * 512;

    // ---- filter scan over own 512 segment (uniform s_load candidates) ----
    for (int g = 0; g < 64; ++g) {
#pragma unroll
        for (int u = 0; u < 8; ++u) {
            int jj = g * 8 + u;
            float4 cd = xb[cbase + jj];             // uniform addr -> s_load
            float dotf = fmaf(cd.z, me.z, fmaf(cd.y, me.y, cd.x * me.x));
            float df = fmaf(-2.0f, dotf, cd.w);
            if (df < T) { ring[cnt * 64 + lane] = (unsigned short)jj; ++cnt; }
        }
        if (__any(cnt >= 8)) { DRAIN16(); }
        if (g == 1 || g == 3 || (g & 7) == 7) { TSYNC(); }
    }
    DRAIN16();

    // ---- two-stage ordered merge (preserves s-ascending insertion order) ----
    __syncthreads();                    // all rings dead; part overlay begins
    if (w < 4) {
#pragma unroll
        for (int e = 0; e < 16; ++e)
            part[(w * 16 + e) * 64 + lane] = make_float2(bd[e], __int_as_float(bi[e]));
    }
    __syncthreads();
    if (w == 0) {                       // merge s=1..3 into own regs
        for (int s = 1; s < 4; ++s) {
#pragma unroll
            for (int e = 0; e < 16; ++e) {
                float2 v = part[(s * 16 + e) * 64 + lane];
                if (v.x >= bd[15]) break;
                float d_ = v.x; int j_ = __float_as_int(v.y);
                INSERT16(d_, j_);
            }
        }
    }
    __syncthreads();
    if (w >= 4) {
#pragma unroll
        for (int e = 0; e < 16; ++e)
            part[((w - 4) * 16 + e) * 64 + lane] = make_float2(bd[e], __int_as_float(bi[e]));
    }
    __syncthreads();
    if (w == 0) {                       // merge s=4..7, then store
        for (int s = 0; s < 4; ++s) {
#pragma unroll
            for (int e = 0; e < 16; ++e) {
                float2 v = part[(s * 16 + e) * 64 + lane];
                if (v.x >= bd[15]) break;
                float d_ = v.x; int j_ = __float_as_int(v.y);
                INSERT16(d_, j_);
            }
        }
        int4* op = (int4*)(out + ((size_t)b * NP + qbase + lane) * 16);
        op[0] = make_int4(bi[0], bi[1], bi[2], bi[3]);
        op[1] = make_int4(bi[4], bi[5], bi[6], bi[7]);
        op[2] = make_int4(bi[8], bi[9], bi[10], bi[11]);
        op[3] = make_int4(bi[12], bi[13], bi[14], bi[15]);
    }
}

// WeightNet + aggregation (vector) + final linear via MFMA + LeakyReLU.
// block = 256 threads (4 waves), 16 points per block.
__global__ __launch_bounds__(256) void k_wagg(
    const float4* __restrict__ xyzt, const int* __restrict__ knn,
    const float* __restrict__ ptst, const uint4* __restrict__ bfrag,
    const float* __restrict__ w0, const float* __restrict__ b0,
    const float* __restrict__ w1, const float* __restrict__ b1,
    const float* __restrict__ w2, const float* __restrict__ b2,
    const float* __restrict__ linb, float* __restrict__ out) {
    __shared__ float wkl[256 * 16];    // 16KB weightnet outputs (fp32, swizzled)
    __shared__ float4 rel4[256];       // 4KB  rel coords + neighbor idx
    __shared__ uint4 aggL4[16 * 128];  // 32KB bf16 A-tile [16 p][1024 k], swizzled
    char* aggL = (char*)aggL4;

    int tid = threadIdx.x;
    int wid = tid >> 6, lane = tid & 63;
    int q0 = blockIdx.x * 16;          // global point base
    int b = q0 >> 12;
    int n0 = q0 & (NP - 1);
    size_t bN = (size_t)b * NP;

    // ---------------- phase 1: WeightNet, all 16 points x 16 neighbors
    {
        int pw = lane >> 4, k = lane & 15;
        int p = wid * 4 + pw;
        int r = p * 16 + k;
        int q = q0 + p;
        int j = knn[(size_t)q * 16 + k];
        float4 pj = xyzt[bN + j];
        float4 pq = xyzt[q];
        float rx = pj.x - pq.x, ry = pj.y - pq.y, rz = pj.z - pq.z;
        float h0[8], h1[8], wv[16];
#pragma unroll
        for (int o = 0; o < 8; ++o) {
            float a = w0[o * 3 + 0] * rx + w0[o * 3 + 1] * ry + w0[o * 3 + 2] * rz + b0[o];
            h0[o] = a > 0.0f ? a : 0.0f;
        }
#pragma unroll
        for (int o = 0; o < 8; ++o) {
            float a = b1[o];
#pragma unroll
            for (int c2 = 0; c2 < 8; ++c2) a += w1[o * 8 + c2] * h0[c2];
            h1[o] = a > 0.0f ? a : 0.0f;
        }
#pragma unroll
        for (int o = 0; o < 16; ++o) {
            float a = b2[o];
#pragma unroll
            for (int c2 = 0; c2 < 8; ++c2) a += w2[o * 8 + c2] * h1[c2];
            wv[o] = a > 0.0f ? a : 0.0f;
        }
        int f = (r >> 1) & 3;
#pragma unroll
        for (int s = 0; s < 4; ++s)
            *(float4*)&wkl[r * 16 + ((s ^ f) << 2)] =
                make_float4(wv[s * 4], wv[s * 4 + 1], wv[s * 4 + 2], wv[s * 4 + 3]);
        rel4[r] = make_float4(rx, ry, rz, __int_as_float(j));
    }
    __syncthreads();

    // ------------ phase 2: agg rows in registers -> bf16 A-tile in LDS
    for (int u = 0; u < 4; ++u) {
        int p = wid * 4 + u;
        float acc[16];
#pragma unroll
        for (int w = 0; w < 16; ++w) acc[w] = 0.0f;
#pragma unroll
        for (int k = 0; k < 16; ++k) {
            int r = p * 16 + k;
            float4 rj = rel4[r];
            int j = __float_as_int(rj.w);
            float v;
            if (lane >= 3) v = ptst[(bN + j) * 64 + (lane - 3)];
            else v = (lane == 0) ? rj.x : ((lane == 1) ? rj.y : rj.z);
            int f = (r >> 1) & 3;
#pragma unroll
            for (int s = 0; s < 4; ++s) {
                float4 wv4 = *(const float4*)&wkl[r * 16 + ((s ^ f) << 2)];
                acc[s * 4 + 0] = fmaf(v, wv4.x, acc[s * 4 + 0]);
                acc[s * 4 + 1] = fmaf(v, wv4.y, acc[s * 4 + 1]);
                acc[s * 4 + 2] = fmaf(v, wv4.z, acc[s * 4 + 2]);
                acc[s * 4 + 3] = fmaf(v, wv4.w, acc[s * 4 + 3]);
            }
        }
        unsigned int pk[8];
#pragma unroll
        for (int i = 0; i < 8; ++i)
            pk[i] = ((unsigned int)f2bf(acc[2 * i + 1]) << 16) | f2bf(acc[2 * i]);
        int cx = lane ^ (p & 7);
        *(uint4*)&aggL[p * 2048 + cx * 16]        = make_uint4(pk[0], pk[1], pk[2], pk[3]);
        *(uint4*)&aggL[p * 2048 + 1024 + cx * 16] = make_uint4(pk[4], pk[5], pk[6], pk[7]);
    }
    __syncthreads();

    // ------------ phase 3: C[16 p][16 o] per wave via MFMA, K = 1024
    f32x4 cacc = {0.0f, 0.0f, 0.0f, 0.0f};
    {
        int p_ = lane & 15, oct = lane >> 4;
        int h = oct & 1, chalf = oct >> 1;
        int pbase = p_ * 2048 + h * 1024;
        int px = p_ & 7;
#pragma unroll 4
        for (int ks = 0; ks < 32; ++ks) {
            int c = ks * 2 + chalf;
            bf16x8 av = *(const bf16x8*)&aggL[pbase + ((c ^ px) << 4)];
            bf16x8 bv = *(const bf16x8*)&bfrag[(ks * 4 + wid) * 64 + lane];
            cacc = __builtin_amdgcn_mfma_f32_16x16x32_bf16(av, bv, cacc, 0, 0, 0);
        }
    }
    __syncthreads();                    // wkl region dead -> reuse for C transpose
    float* cout = wkl;                  // [64 o][17 p] fp32
    {
        int o = wid * 16 + (lane & 15);
        int rbase = (lane >> 4) * 4;    // C/D row = (lane>>4)*4 + reg   [m89]
#pragma unroll
        for (int reg = 0; reg < 4; ++reg)
            cout[o * 17 + rbase + reg] = cacc[reg];
    }
    __syncthreads();
    {
        int oo = tid >> 2, pq = tid & 3;
        float bias = linb[oo];
        float res[4];
#pragma unroll
        for (int e = 0; e < 4; ++e) {
            float s = cout[oo * 17 + pq * 4 + e] + bias;
            res[e] = s > 0.0f ? s : 0.1f * s;
        }
        *(float4*)&out[((size_t)(b * 64 + oo)) * NP + n0 + pq * 4] =
            make_float4(res[0], res[1], res[2], res[3]);
    }
}

extern "C" void kernel_launch(void* const* d_in, const int* in_sizes, int n_in,
                              void* d_out, int out_size, void* d_ws, size_t ws_size,
                              hipStream_t stream) {
    const float* xyz  = (const float*)d_in[0];
    const float* pts  = (const float*)d_in[1];
    const float* w0   = (const float*)d_in[2];
    const float* b0   = (const float*)d_in[3];
    const float* w1   = (const float*)d_in[4];
    const float* b1   = (const float*)d_in[5];
    const float* w2   = (const float*)d_in[6];
    const float* b2   = (const float*)d_in[7];
    const float* lw   = (const float*)d_in[8];
    const float* linb = (const float*)d_in[9];
    float* out = (float*)d_out;

    char* ws = (char*)d_ws;
    float4* xyzt  = (float4*)(ws + OFF_XYZT);
    int*    idx   = (int*)(ws + OFF_IDX);
    float*  ptst  = (float*)(ws + OFF_PTST);
    uint4*  bfrag = (uint4*)(ws + OFF_BFRAG);

    k_prep_xyz<<<BN / 256, 256, 0, stream>>>(xyz, xyzt);
    k_prep_ptst<<<NBATCH * (NP / 64), 256, 0, stream>>>(pts, ptst);
    k_prep_bfrag<<<32, 256, 0, stream>>>(lw, bfrag);
    k_knn<<<512, 512, 0, stream>>>(xyzt, idx);
    k_wagg<<<BN / 16, 256, 0, stream>>>(xyzt, idx, ptst, bfrag,
                                        w0, b0, w1, b1, w2, b2, linb, out);
    (void)in_sizes; (void)n_in; (void)out_size; (void)ws_size;
}

// Round 9
// 275.656 us; speedup vs baseline: 1.0483x; 1.0483x over previous
//
#include <hip/hip_runtime.h>
#include <hip/hip_bf16.h>

#define NBATCH 8
#define NP     4096
#define ND     61
#define NK     16
#define BN     (NBATCH*NP)

// ws layout (bytes)
#define OFF_XYZT  0                          // float4 * BN       = 524288
#define OFF_IDX   (OFF_XYZT + BN*16)         // int * BN*16       = 2097152
#define OFF_PTST  (OFF_IDX + BN*64)          // float * BN*64     = 8388608
#define OFF_BFRAG (OFF_PTST + BN*256)        // uint4 * 8192      = 131072
// total < 11272192 bytes (same budget as R2-R8 — known safe)

typedef __attribute__((ext_vector_type(8))) short bf16x8;
typedef __attribute__((ext_vector_type(4))) float f32x4;

static __device__ __forceinline__ unsigned short f2bf(float x) {
    unsigned int u = __float_as_uint(x);
    return (unsigned short)((u + 0x7fffu + ((u >> 16) & 1u)) >> 16);   // RNE
}

__global__ __launch_bounds__(256) void k_prep_xyz(const float* __restrict__ xyz,
                                                  float4* __restrict__ xyzt) {
#pragma clang fp contract(off)
    int t = blockIdx.x * 256 + threadIdx.x;      // 0..BN-1
    int b = t >> 12, n = t & (NP - 1);
    const float* base = xyz + (size_t)b * 3 * NP + n;
    float x = base[0], y = base[NP], z = base[2 * NP];
    // match numpy: sum(xyz*xyz, -1) = ((x*x + y*y) + z*z), no FMA fusion
    float sq = ((x * x) + (y * y)) + (z * z);
    xyzt[t] = make_float4(x, y, z, sq);
}

__global__ __launch_bounds__(256) void k_prep_ptst(const float* __restrict__ pts,
                                                   float* __restrict__ ptst) {
    __shared__ float tile[64][65];
    int blk = blockIdx.x;                 // NBATCH * (NP/64) = 512
    int b = blk >> 6; int n0 = (blk & 63) << 6;
    int tid = threadIdx.x; int rg = tid >> 6; int cl = tid & 63;
#pragma unroll
    for (int d0 = 0; d0 < 64; d0 += 4) {
        int d = d0 + rg;
        if (d < ND) tile[d][cl] = pts[((size_t)b * ND + d) * NP + n0 + cl];
    }
    __syncthreads();
#pragma unroll
    for (int r = 0; r < 16; ++r) {
        int n1 = r * 4 + rg;
        float v = (cl < ND) ? tile[cl][n1] : 0.0f;
        ptst[((size_t)b * NP + n0 + n1) * 64 + cl] = v;
    }
}

// B fragments for mfma_f32_16x16x32_bf16: B[k][n] = lin_w[n][k].
__global__ __launch_bounds__(256) void k_prep_bfrag(const float* __restrict__ lw,
                                                    uint4* __restrict__ bfrag) {
    int e = blockIdx.x * 256 + threadIdx.x;   // 32 blocks -> 8192 threads
    int lane = e & 63, nt = (e >> 6) & 3, ks = e >> 8;
    int k0 = ks * 32 + (lane >> 4) * 8;
    int n = nt * 16 + (lane & 15);
    const float* src = lw + (size_t)n * 1024 + k0;
    unsigned int pk[4];
#pragma unroll
    for (int i = 0; i < 4; ++i)
        pk[i] = ((unsigned int)f2bf(src[2 * i + 1]) << 16) | f2bf(src[2 * i]);
    bfrag[e] = make_uint4(pk[0], pk[1], pk[2], pk[3]);
}

#define INSERT16(dv, jv)                                            \
    do {                                                            \
        bd[15] = (dv); bi[15] = (jv);                               \
        _Pragma("unroll")                                           \
        for (int s_ = 15; s_ > 0; --s_) {                           \
            bool sw_ = bd[s_] < bd[s_ - 1];                         \
            float td_ = bd[s_]; int ti_ = bi[s_];                   \
            bd[s_]     = sw_ ? bd[s_ - 1] : td_;                    \
            bi[s_]     = sw_ ? bi[s_ - 1] : ti_;                    \
            bd[s_ - 1] = sw_ ? td_ : bd[s_ - 1];                    \
            bi[s_ - 1] = sw_ ? ti_ : bi[s_ - 1];                    \
        }                                                           \
    } while (0)

// Drain the idx-ring: recompute EXACT (numpy op-order) distance from the LDS
// tile via _rn intrinsics, strict-< check, insert. Slot loop ROLLED.
#define DRAIN16(basev)                                                        \
    do {                                                                      \
        for (int r_ = 0; r_ < 16; ++r_) {                                     \
            if (!__any(r_ < cnt)) break;                                      \
            if (r_ < cnt) {                                                   \
                int loc_ = ring[r_ * 64 + lane];                              \
                float4 cd_ = tile[loc_];                                      \
                float dot_ = __fadd_rn(__fadd_rn(__fmul_rn(cd_.x, me.x),      \
                                                 __fmul_rn(cd_.y, me.y)),     \
                                       __fmul_rn(cd_.z, me.z));               \
                float dist_ = __fsub_rn(__fadd_rn(me.w, cd_.w),               \
                                        __fmul_rn(2.0f, dot_));               \
                if (dist_ < bd[15]) {                                         \
                    int gj_ = (basev) + loc_;                                 \
                    INSERT16(dist_, gj_);                                     \
                }                                                             \
            }                                                                 \
        }                                                                     \
        cnt = 0;                                                              \
        T = fminf(T, (bd[15] - me.w) + 1.0e-3f);                              \
    } while (0)

// share thresholds across the 8 waves (all serve the same 64 queries):
// T can only tighten toward (global d16 + margin); stale reads are looser->safe
#define TSYNC()                                                               \
    do {                                                                      \
        Tsh[w * 64 + lane] = bd[15];                                          \
        float tm_ = Tsh[lane];                                                \
        _Pragma("unroll")                                                     \
        for (int v_ = 1; v_ < 8; ++v_) tm_ = fminf(tm_, Tsh[v_ * 64 + lane]); \
        T = fminf(T, (tm_ - me.w) + 1.0e-3f);                                 \
    } while (0)

// 8 waves per block; wave w scans candidate range [w*512, w*512+512) for the
// block's 64 queries (lane=query); in-block merge of 8 sorted 16-lists.
// Batched filter: 8 candidates -> df regs -> ONE __any branch per group;
// survivor stores + cnt check only inside the rare group-hit path.
__global__ __launch_bounds__(512) void k_knn(const float4* __restrict__ xyzt,
                                             int* __restrict__ out) {
    __shared__ char smem[65536 + 2048];
    int tid = threadIdx.x;
    int w = __builtin_amdgcn_readfirstlane(tid >> 6);   // wave id, SGPR-uniform
    int lane = tid & 63;
    int blk = blockIdx.x;               // 512 blocks
    int b = blk >> 6;
    int qbase = (blk & 63) << 6;
    const float4* xb = xyzt + (size_t)b * NP;

    float4* tile = (float4*)(smem + w * 4096);        // 256 float4, wave-private
    int*    ring = (int*)(smem + 32768 + w * 4096);   // [16][64] int, wave-private
    float*  Tsh  = (float*)(smem + 65536);            // [8][64] shared bounds

    float4 me = xb[qbase + lane];
    float bd[16]; int bi[16];
#pragma unroll
    for (int i = 0; i < 16; ++i) { bd[i] = 3.0e38f; bi[i] = 0; }
    int cnt = 0;
    float T = 3.0e38f;                  // filter threshold (on df = dist - me.w)
    Tsh[w * 64 + lane] = 3.0e38f;
    __syncthreads();                    // Tsh init visible before any TSYNC read

    int cbase = w * 512;
    for (int half = 0; half < 2; ++half) {
        int base = cbase + half * 256;
#pragma unroll
        for (int r = 0; r < 4; ++r)
            tile[lane + r * 64] = xb[base + lane + r * 64];
        // tile is wave-private: compiler inserts lgkm waits, no barrier needed
        for (int seg = 0; seg < 4; ++seg) {
            for (int g = 0; g < 8; ++g) {
                int j0 = seg * 64 + g * 8;
                float dfv[8];
                bool anyhit = false;
#pragma unroll
                for (int u = 0; u < 8; ++u) {
                    float4 cd = tile[j0 + u];
                    // fused filter: df = cd.w - 2*dot vs T = d16bound - me.w + m
                    float dotf = fmaf(cd.z, me.z, fmaf(cd.y, me.y, cd.x * me.x));
                    dfv[u] = fmaf(-2.0f, dotf, cd.w);
                    anyhit |= (dfv[u] < T);
                }
                if (__any(anyhit)) {    // rare once T converges
#pragma unroll
                    for (int u = 0; u < 8; ++u) {
                        if (dfv[u] < T) { ring[cnt * 64 + lane] = j0 + u; ++cnt; }
                    }
                    if (__any(cnt >= 8)) { DRAIN16(base); }
                }
                if (half == 0 && seg == 0 && (g == 1 || g == 3)) { TSYNC(); }
            }
            TSYNC();                    // every 64 candidates
        }
        DRAIN16(base);                  // flush before tile overwrite
    }

    // publish sorted partials to LDS: part[s][e][q] (lane-consecutive)
    __syncthreads();
    float2* part = (float2*)smem;       // [8][16][64] float2 = 64KB overlay
#pragma unroll
    for (int e = 0; e < 16; ++e)
        part[(w * 16 + e) * 64 + lane] = make_float2(bd[e], __int_as_float(bi[e]));
    __syncthreads();

    if (w == 0) {
        // lane merges its query's 8 sorted lists (s ascending = index ascending,
        // strict < keeps top_k's lower-index-first tie behavior)
        float bd[16]; int bi[16];
#pragma unroll
        for (int e = 0; e < 16; ++e) {
            float2 v = part[e * 64 + lane];
            bd[e] = v.x; bi[e] = __float_as_int(v.y);
        }
        for (int s = 1; s < 8; ++s) {
#pragma unroll
            for (int e = 0; e < 16; ++e) {
                float2 v = part[(s * 16 + e) * 64 + lane];
                if (v.x >= bd[15]) break;
                float d_ = v.x; int j_ = __float_as_int(v.y);
                INSERT16(d_, j_);
            }
        }
        int4* op = (int4*)(out + ((size_t)b * NP + qbase + lane) * 16);
        op[0] = make_int4(bi[0], bi[1], bi[2], bi[3]);
        op[1] = make_int4(bi[4], bi[5], bi[6], bi[7]);
        op[2] = make_int4(bi[8], bi[9], bi[10], bi[11]);
        op[3] = make_int4(bi[12], bi[13], bi[14], bi[15]);
    }
}

// WeightNet + aggregation (vector) + final linear via MFMA + LeakyReLU.
// block = 256 threads (4 waves), 16 points per block.
__global__ __launch_bounds__(256) void k_wagg(
    const float4* __restrict__ xyzt, const int* __restrict__ knn,
    const float* __restrict__ ptst, const uint4* __restrict__ bfrag,
    const float* __restrict__ w0, const float* __restrict__ b0,
    const float* __restrict__ w1, const float* __restrict__ b1,
    const float* __restrict__ w2, const float* __restrict__ b2,
    const float* __restrict__ linb, float* __restrict__ out) {
    __shared__ float wkl[256 * 16];    // 16KB weightnet outputs (fp32, swizzled)
    __shared__ float4 rel4[256];       // 4KB  rel coords + neighbor idx
    __shared__ uint4 aggL4[16 * 128];  // 32KB bf16 A-tile [16 p][1024 k], swizzled
    char* aggL = (char*)aggL4;

    int tid = threadIdx.x;
    int wid = tid >> 6, lane = tid & 63;
    int q0 = blockIdx.x * 16;          // global point base
    int b = q0 >> 12;
    int n0 = q0 & (NP - 1);
    size_t bN = (size_t)b * NP;

    // ---------------- phase 1: WeightNet, all 16 points x 16 neighbors
    {
        int pw = lane >> 4, k = lane & 15;
        int p = wid * 4 + pw;
        int r = p * 16 + k;
        int q = q0 + p;
        int j = knn[(size_t)q * 16 + k];
        float4 pj = xyzt[bN + j];
        float4 pq = xyzt[q];
        float rx = pj.x - pq.x, ry = pj.y - pq.y, rz = pj.z - pq.z;
        float h0[8], h1[8], wv[16];
#pragma unroll
        for (int o = 0; o < 8; ++o) {
            float a = w0[o * 3 + 0] * rx + w0[o * 3 + 1] * ry + w0[o * 3 + 2] * rz + b0[o];
            h0[o] = a > 0.0f ? a : 0.0f;
        }
#pragma unroll
        for (int o = 0; o < 8; ++o) {
            float a = b1[o];
#pragma unroll
            for (int c2 = 0; c2 < 8; ++c2) a += w1[o * 8 + c2] * h0[c2];
            h1[o] = a > 0.0f ? a : 0.0f;
        }
#pragma unroll
        for (int o = 0; o < 16; ++o) {
            float a = b2[o];
#pragma unroll
            for (int c2 = 0; c2 < 8; ++c2) a += w2[o * 8 + c2] * h1[c2];
            wv[o] = a > 0.0f ? a : 0.0f;
        }
        int f = (r >> 1) & 3;
#pragma unroll
        for (int s = 0; s < 4; ++s)
            *(float4*)&wkl[r * 16 + ((s ^ f) << 2)] =
                make_float4(wv[s * 4], wv[s * 4 + 1], wv[s * 4 + 2], wv[s * 4 + 3]);
        rel4[r] = make_float4(rx, ry, rz, __int_as_float(j));
    }
    __syncthreads();

    // ------------ phase 2: agg rows in registers -> bf16 A-tile in LDS
    for (int u = 0; u < 4; ++u) {
        int p = wid * 4 + u;
        float acc[16];
#pragma unroll
        for (int w = 0; w < 16; ++w) acc[w] = 0.0f;
#pragma unroll
        for (int k = 0; k < 16; ++k) {
            int r = p * 16 + k;
            float4 rj = rel4[r];
            int j = __float_as_int(rj.w);
            float v;
            if (lane >= 3) v = ptst[(bN + j) * 64 + (lane - 3)];
            else v = (lane == 0) ? rj.x : ((lane == 1) ? rj.y : rj.z);
            int f = (r >> 1) & 3;
#pragma unroll
            for (int s = 0; s < 4; ++s) {
                float4 wv4 = *(const float4*)&wkl[r * 16 + ((s ^ f) << 2)];
                acc[s * 4 + 0] = fmaf(v, wv4.x, acc[s * 4 + 0]);
                acc[s * 4 + 1] = fmaf(v, wv4.y, acc[s * 4 + 1]);
                acc[s * 4 + 2] = fmaf(v, wv4.z, acc[s * 4 + 2]);
                acc[s * 4 + 3] = fmaf(v, wv4.w, acc[s * 4 + 3]);
            }
        }
        unsigned int pk[8];
#pragma unroll
        for (int i = 0; i < 8; ++i)
            pk[i] = ((unsigned int)f2bf(acc[2 * i + 1]) << 16) | f2bf(acc[2 * i]);
        int cx = lane ^ (p & 7);
        *(uint4*)&aggL[p * 2048 + cx * 16]        = make_uint4(pk[0], pk[1], pk[2], pk[3]);
        *(uint4*)&aggL[p * 2048 + 1024 + cx * 16] = make_uint4(pk[4], pk[5], pk[6], pk[7]);
    }
    __syncthreads();

    // ------------ phase 3: C[16 p][16 o] per wave via MFMA, K = 1024
    f32x4 cacc = {0.0f, 0.0f, 0.0f, 0.0f};
    {
        int p_ = lane & 15, oct = lane >> 4;
        int h = oct & 1, chalf = oct >> 1;
        int pbase = p_ * 2048 + h * 1024;
        int px = p_ & 7;
#pragma unroll 4
        for (int ks = 0; ks < 32; ++ks) {
            int c = ks * 2 + chalf;
            bf16x8 av = *(const bf16x8*)&aggL[pbase + ((c ^ px) << 4)];
            bf16x8 bv = *(const bf16x8*)&bfrag[(ks * 4 + wid) * 64 + lane];
            cacc = __builtin_amdgcn_mfma_f32_16x16x32_bf16(av, bv, cacc, 0, 0, 0);
        }
    }
    __syncthreads();                    // wkl region dead -> reuse for C transpose
    float* cout = wkl;                  // [64 o][17 p] fp32
    {
        int o = wid * 16 + (lane & 15);
        int rbase = (lane >> 4) * 4;    // C/D row = (lane>>4)*4 + reg   [m89]
#pragma unroll
        for (int reg = 0; reg < 4; ++reg)
            cout[o * 17 + rbase + reg] = cacc[reg];
    }
    __syncthreads();
    {
        int oo = tid >> 2, pq = tid & 3;
        float bias = linb[oo];
        float res[4];
#pragma unroll
        for (int e = 0; e < 4; ++e) {
            float s = cout[oo * 17 + pq * 4 + e] + bias;
            res[e] = s > 0.0f ? s : 0.1f * s;
        }
        *(float4*)&out[((size_t)(b * 64 + oo)) * NP + n0 + pq * 4] =
            make_float4(res[0], res[1], res[2], res[3]);
    }
}

extern "C" void kernel_launch(void* const* d_in, const int* in_sizes, int n_in,
                              void* d_out, int out_size, void* d_ws, size_t ws_size,
                              hipStream_t stream) {
    const float* xyz  = (const float*)d_in[0];
    const float* pts  = (const float*)d_in[1];
    const float* w0   = (const float*)d_in[2];
    const float* b0   = (const float*)d_in[3];
    const float* w1   = (const float*)d_in[4];
    const float* b1   = (const float*)d_in[5];
    const float* w2   = (const float*)d_in[6];
    const float* b2   = (const float*)d_in[7];
    const float* lw   = (const float*)d_in[8];
    const float* linb = (const float*)d_in[9];
    float* out = (float*)d_out;

    char* ws = (char*)d_ws;
    float4* xyzt  = (float4*)(ws + OFF_XYZT);
    int*    idx   = (int*)(ws + OFF_IDX);
    float*  ptst  = (float*)(ws + OFF_PTST);
    uint4*  bfrag = (uint4*)(ws + OFF_BFRAG);

    k_prep_xyz<<<BN / 256, 256, 0, stream>>>(xyz, xyzt);
    k_prep_ptst<<<NBATCH * (NP / 64), 256, 0, stream>>>(pts, ptst);
    k_prep_bfrag<<<32, 256, 0, stream>>>(lw, bfrag);
    k_knn<<<512, 512, 0, stream>>>(xyzt, idx);
    k_wagg<<<BN / 16, 256, 0, stream>>>(xyzt, idx, ptst, bfrag,
                                        w0, b0, w1, b1, w2, b2, linb, out);
    (void)in_sizes; (void)n_in; (void)out_size; (void)ws_size;
}

// Round 10
// 222.382 us; speedup vs baseline: 1.2995x; 1.2396x over previous
//
#include <hip/hip_runtime.h>
#include <hip/hip_bf16.h>

#define NBATCH 8
#define NP     4096
#define ND     61
#define NK     16
#define BN     (NBATCH*NP)

// ws layout (bytes)
#define OFF_XYZT  0                          // float4 * BN       = 524288
#define OFF_IDX   (OFF_XYZT + BN*16)         // int * BN*16       = 2097152
#define OFF_PTST  (OFF_IDX + BN*64)         // float * BN*64     = 8388608
#define OFF_BFRAG (OFF_PTST + BN*256)        // uint4 * 8192      = 131072
// total < 11272192 bytes (same budget as R2-R9 — known safe)

typedef __attribute__((ext_vector_type(8))) short bf16x8;
typedef __attribute__((ext_vector_type(4))) float f32x4;

static __device__ __forceinline__ unsigned short f2bf(float x) {
    unsigned int u = __float_as_uint(x);
    return (unsigned short)((u + 0x7fffu + ((u >> 16) & 1u)) >> 16);   // RNE
}

// merged prep: blocks 0..127 xyz-pack, 128..639 points-transpose, 640..671 bfrag
__global__ __launch_bounds__(256) void k_prep(const float* __restrict__ xyz,
                                              const float* __restrict__ pts,
                                              const float* __restrict__ lw,
                                              float4* __restrict__ xyzt,
                                              float* __restrict__ ptst,
                                              uint4* __restrict__ bfrag) {
#pragma clang fp contract(off)
    __shared__ float tile[64][65];
    int blk = blockIdx.x;
    int tid = threadIdx.x;
    if (blk < 128) {
        int t = blk * 256 + tid;             // 0..BN-1
        int b = t >> 12, n = t & (NP - 1);
        const float* base = xyz + (size_t)b * 3 * NP + n;
        float x = base[0], y = base[NP], z = base[2 * NP];
        // match numpy: sum(xyz*xyz,-1) = ((x*x + y*y) + z*z), no FMA fusion
        float sq = ((x * x) + (y * y)) + (z * z);
        xyzt[t] = make_float4(x, y, z, sq);
    } else if (blk < 640) {
        int bb = blk - 128;                  // 512 transpose blocks
        int b = bb >> 6; int n0 = (bb & 63) << 6;
        int rg = tid >> 6; int cl = tid & 63;
#pragma unroll
        for (int d0 = 0; d0 < 64; d0 += 4) {
            int d = d0 + rg;
            if (d < ND) tile[d][cl] = pts[((size_t)b * ND + d) * NP + n0 + cl];
        }
        __syncthreads();
#pragma unroll
        for (int r = 0; r < 16; ++r) {
            int n1 = r * 4 + rg;
            float v = (cl < ND) ? tile[cl][n1] : 0.0f;
            ptst[((size_t)b * NP + n0 + n1) * 64 + cl] = v;
        }
    } else {
        int e = (blk - 640) * 256 + tid;     // 0..8191
        int lane = e & 63, nt = (e >> 6) & 3, ks = e >> 8;
        int k0 = ks * 32 + (lane >> 4) * 8;
        int n = nt * 16 + (lane & 15);
        const float* src = lw + (size_t)n * 1024 + k0;
        unsigned int pk[4];
#pragma unroll
        for (int i = 0; i < 4; ++i)
            pk[i] = ((unsigned int)f2bf(src[2 * i + 1]) << 16) | f2bf(src[2 * i]);
        bfrag[e] = make_uint4(pk[0], pk[1], pk[2], pk[3]);
    }
}

#define INSERT16(dv, jv)                                            \
    do {                                                            \
        bd[15] = (dv); bi[15] = (jv);                               \
        _Pragma("unroll")                                           \
        for (int s_ = 15; s_ > 0; --s_) {                           \
            bool sw_ = bd[s_] < bd[s_ - 1];                         \
            float td_ = bd[s_]; int ti_ = bi[s_];                   \
            bd[s_]     = sw_ ? bd[s_ - 1] : td_;                    \
            bi[s_]     = sw_ ? bi[s_ - 1] : ti_;                    \
            bd[s_ - 1] = sw_ ? td_ : bd[s_ - 1];                    \
            bi[s_ - 1] = sw_ ? ti_ : bi[s_ - 1];                    \
        }                                                           \
    } while (0)

// Drain the idx-ring: recompute EXACT (numpy op-order) distance from the LDS
// tile via _rn intrinsics, strict-< check, insert. Slot loop ROLLED.
#define DRAIN16(basev)                                                        \
    do {                                                                      \
        for (int r_ = 0; r_ < 16; ++r_) {                                     \
            if (!__any(r_ < cnt)) break;                                      \
            if (r_ < cnt) {                                                   \
                int loc_ = ring[r_ * 64 + lane];                              \
                float4 cd_ = tile[loc_];                                      \
                float dot_ = __fadd_rn(__fadd_rn(__fmul_rn(cd_.x, me.x),      \
                                                 __fmul_rn(cd_.y, me.y)),     \
                                       __fmul_rn(cd_.z, me.z));               \
                float dist_ = __fsub_rn(__fadd_rn(me.w, cd_.w),               \
                                        __fmul_rn(2.0f, dot_));               \
                if (dist_ < bd[15]) {                                         \
                    int gj_ = (basev) + loc_;                                 \
                    INSERT16(dist_, gj_);                                     \
                }                                                             \
            }                                                                 \
        }                                                                     \
        cnt = 0;                                                              \
        T = fminf(T, (bd[15] - me.w) + 1.0e-3f);                              \
    } while (0)

// share thresholds across the 8 waves (all serve the same 64 queries):
// T can only tighten toward (global d16 + margin); stale reads are looser->safe
#define TSYNC()                                                               \
    do {                                                                      \
        Tsh[w * 64 + lane] = bd[15];                                          \
        float tm_ = Tsh[lane];                                                \
        _Pragma("unroll")                                                     \
        for (int v_ = 1; v_ < 8; ++v_) tm_ = fminf(tm_, Tsh[v_ * 64 + lane]); \
        T = fminf(T, (tm_ - me.w) + 1.0e-3f);                                 \
    } while (0)

// 8 waves per block; wave w scans candidate range [w*512, w*512+512) for the
// block's 64 queries (lane=query); in-block merge of 8 sorted 16-lists.
// Best-known variant (R5 structure, 155us): fused filter + TSYNC + exact drain.
__global__ __launch_bounds__(512) void k_knn(const float4* __restrict__ xyzt,
                                             int* __restrict__ out) {
    __shared__ char smem[65536 + 2048];
    int tid = threadIdx.x;
    int w = tid >> 6, lane = tid & 63;
    int blk = blockIdx.x;               // 512 blocks
    int b = blk >> 6;
    int qbase = (blk & 63) << 6;
    const float4* xb = xyzt + (size_t)b * NP;

    float4* tile = (float4*)(smem + w * 4096);        // 256 float4, wave-private
    int*    ring = (int*)(smem + 32768 + w * 4096);   // [16][64] int, wave-private
    float*  Tsh  = (float*)(smem + 65536);            // [8][64] shared thresholds

    float4 me = xb[qbase + lane];
    float bd[16]; int bi[16];
#pragma unroll
    for (int i = 0; i < 16; ++i) { bd[i] = 3.0e38f; bi[i] = 0; }
    int cnt = 0;
    float T = 3.0e38f;                  // filter threshold (on df = dist - me.w)
    Tsh[w * 64 + lane] = 3.0e38f;
    __syncthreads();                    // Tsh init visible before any TSYNC read

    int cbase = w * 512;
    for (int half = 0; half < 2; ++half) {
        int base = cbase + half * 256;
#pragma unroll
        for (int r = 0; r < 4; ++r)
            tile[lane + r * 64] = xb[base + lane + r * 64];
        // wave-private tile: compiler inserts lgkm waits, no barrier needed
        for (int seg = 0; seg < 4; ++seg) {
            for (int g = 0; g < 8; ++g) {
                int j0 = seg * 64 + g * 8;
#pragma unroll
                for (int u = 0; u < 8; ++u) {
                    int jj = j0 + u;
                    float4 cd = tile[jj];
                    // fused filter: df = cd.w - 2*dot vs T = d16bound - me.w + m
                    float dotf = fmaf(cd.z, me.z, fmaf(cd.y, me.y, cd.x * me.x));
                    float df = fmaf(-2.0f, dotf, cd.w);
                    if (df < T) { ring[cnt * 64 + lane] = jj; ++cnt; }
                }
                if (__any(cnt >= 8)) { DRAIN16(base); }
                if (half == 0 && seg == 0 && (g == 1 || g == 3)) { TSYNC(); }
            }
            TSYNC();                    // every 64 candidates
        }
        DRAIN16(base);                  // flush before tile overwrite
    }

    // publish sorted partials to LDS: part[s][e][q] (lane-consecutive)
    __syncthreads();
    float2* part = (float2*)smem;       // [8][16][64] float2 = 64KB overlay
#pragma unroll
    for (int e = 0; e < 16; ++e)
        part[(w * 16 + e) * 64 + lane] = make_float2(bd[e], __int_as_float(bi[e]));
    __syncthreads();

    if (w == 0) {
        // lane merges its query's 8 sorted lists (s ascending = index ascending,
        // strict < keeps top_k's lower-index-first tie behavior)
        float bd[16]; int bi[16];
#pragma unroll
        for (int e = 0; e < 16; ++e) {
            float2 v = part[e * 64 + lane];
            bd[e] = v.x; bi[e] = __float_as_int(v.y);
        }
        for (int s = 1; s < 8; ++s) {
#pragma unroll
            for (int e = 0; e < 16; ++e) {
                float2 v = part[(s * 16 + e) * 64 + lane];
                if (v.x >= bd[15]) break;
                float d_ = v.x; int j_ = __float_as_int(v.y);
                INSERT16(d_, j_);
            }
        }
        int4* op = (int4*)(out + ((size_t)b * NP + qbase + lane) * 16);
        op[0] = make_int4(bi[0], bi[1], bi[2], bi[3]);
        op[1] = make_int4(bi[4], bi[5], bi[6], bi[7]);
        op[2] = make_int4(bi[8], bi[9], bi[10], bi[11]);
        op[3] = make_int4(bi[12], bi[13], bi[14], bi[15]);
    }
}

// WeightNet + aggregation (vector) + final linear via MFMA + LeakyReLU.
// block = 256 threads (4 waves), 16 points per block.
// Phase 2 gathers are issued in groups of 8 (independent, hoisted) to
// overlap global latency; FMA order unchanged (bit-identical output).
__global__ __launch_bounds__(256) void k_wagg(
    const float4* __restrict__ xyzt, const int* __restrict__ knn,
    const float* __restrict__ ptst, const uint4* __restrict__ bfrag,
    const float* __restrict__ w0, const float* __restrict__ b0,
    const float* __restrict__ w1, const float* __restrict__ b1,
    const float* __restrict__ w2, const float* __restrict__ b2,
    const float* __restrict__ linb, float* __restrict__ out) {
    __shared__ float wkl[256 * 16];    // 16KB weightnet outputs (fp32, swizzled)
    __shared__ float4 rel4[256];       // 4KB  rel coords + neighbor idx
    __shared__ uint4 aggL4[16 * 128];  // 32KB bf16 A-tile [16 p][1024 k], swizzled
    char* aggL = (char*)aggL4;

    int tid = threadIdx.x;
    int wid = tid >> 6, lane = tid & 63;
    int q0 = blockIdx.x * 16;          // global point base
    int b = q0 >> 12;
    int n0 = q0 & (NP - 1);
    size_t bN = (size_t)b * NP;

    // ---------------- phase 1: WeightNet, all 16 points x 16 neighbors
    {
        int pw = lane >> 4, k = lane & 15;
        int p = wid * 4 + pw;
        int r = p * 16 + k;
        int q = q0 + p;
        int j = knn[(size_t)q * 16 + k];
        float4 pj = xyzt[bN + j];
        float4 pq = xyzt[q];
        float rx = pj.x - pq.x, ry = pj.y - pq.y, rz = pj.z - pq.z;
        float h0[8], h1[8], wv[16];
#pragma unroll
        for (int o = 0; o < 8; ++o) {
            float a = w0[o * 3 + 0] * rx + w0[o * 3 + 1] * ry + w0[o * 3 + 2] * rz + b0[o];
            h0[o] = a > 0.0f ? a : 0.0f;
        }
#pragma unroll
        for (int o = 0; o < 8; ++o) {
            float a = b1[o];
#pragma unroll
            for (int c2 = 0; c2 < 8; ++c2) a += w1[o * 8 + c2] * h0[c2];
            h1[o] = a > 0.0f ? a : 0.0f;
        }
#pragma unroll
        for (int o = 0; o < 16; ++o) {
            float a = b2[o];
#pragma unroll
            for (int c2 = 0; c2 < 8; ++c2) a += w2[o * 8 + c2] * h1[c2];
            wv[o] = a > 0.0f ? a : 0.0f;
        }
        int f = (r >> 1) & 3;
#pragma unroll
        for (int s = 0; s < 4; ++s)
            *(float4*)&wkl[r * 16 + ((s ^ f) << 2)] =
                make_float4(wv[s * 4], wv[s * 4 + 1], wv[s * 4 + 2], wv[s * 4 + 3]);
        rel4[r] = make_float4(rx, ry, rz, __int_as_float(j));
    }
    __syncthreads();

    // ------------ phase 2: agg rows in registers -> bf16 A-tile in LDS
    for (int u = 0; u < 4; ++u) {
        int p = wid * 4 + u;
        float acc[16];
#pragma unroll
        for (int w = 0; w < 16; ++w) acc[w] = 0.0f;
#pragma unroll
        for (int kh = 0; kh < 2; ++kh) {
            float vv[8];
#pragma unroll
            for (int kk = 0; kk < 8; ++kk) {       // 8 independent gathers
                int r = p * 16 + kh * 8 + kk;
                float4 rj = rel4[r];
                int j = __float_as_int(rj.w);
                vv[kk] = (lane >= 3) ? ptst[(bN + j) * 64 + (lane - 3)]
                                     : ((lane == 0) ? rj.x : ((lane == 1) ? rj.y : rj.z));
            }
#pragma unroll
            for (int kk = 0; kk < 8; ++kk) {       // FMAs, same order as before
                int r = p * 16 + kh * 8 + kk;
                int f = (r >> 1) & 3;
                float v = vv[kk];
#pragma unroll
                for (int s = 0; s < 4; ++s) {
                    float4 wv4 = *(const float4*)&wkl[r * 16 + ((s ^ f) << 2)];
                    acc[s * 4 + 0] = fmaf(v, wv4.x, acc[s * 4 + 0]);
                    acc[s * 4 + 1] = fmaf(v, wv4.y, acc[s * 4 + 1]);
                    acc[s * 4 + 2] = fmaf(v, wv4.z, acc[s * 4 + 2]);
                    acc[s * 4 + 3] = fmaf(v, wv4.w, acc[s * 4 + 3]);
                }
            }
        }
        unsigned int pk[8];
#pragma unroll
        for (int i = 0; i < 8; ++i)
            pk[i] = ((unsigned int)f2bf(acc[2 * i + 1]) << 16) | f2bf(acc[2 * i]);
        int cx = lane ^ (p & 7);
        *(uint4*)&aggL[p * 2048 + cx * 16]        = make_uint4(pk[0], pk[1], pk[2], pk[3]);
        *(uint4*)&aggL[p * 2048 + 1024 + cx * 16] = make_uint4(pk[4], pk[5], pk[6], pk[7]);
    }
    __syncthreads();

    // ------------ phase 3: C[16 p][16 o] per wave via MFMA, K = 1024
    f32x4 cacc = {0.0f, 0.0f, 0.0f, 0.0f};
    {
        int p_ = lane & 15, oct = lane >> 4;
        int h = oct & 1, chalf = oct >> 1;
        int pbase = p_ * 2048 + h * 1024;
        int px = p_ & 7;
#pragma unroll 4
        for (int ks = 0; ks < 32; ++ks) {
            int c = ks * 2 + chalf;
            bf16x8 av = *(const bf16x8*)&aggL[pbase + ((c ^ px) << 4)];
            bf16x8 bv = *(const bf16x8*)&bfrag[(ks * 4 + wid) * 64 + lane];
            cacc = __builtin_amdgcn_mfma_f32_16x16x32_bf16(av, bv, cacc, 0, 0, 0);
        }
    }
    __syncthreads();                    // wkl region dead -> reuse for C transpose
    float* cout = wkl;                  // [64 o][17 p] fp32
    {
        int o = wid * 16 + (lane & 15);
        int rbase = (lane >> 4) * 4;    // C/D row = (lane>>4)*4 + reg   [m89]
#pragma unroll
        for (int reg = 0; reg < 4; ++reg)
            cout[o * 17 + rbase + reg] = cacc[reg];
    }
    __syncthreads();
    {
        int oo = tid >> 2, pq = tid & 3;
        float bias = linb[oo];
        float res[4];
#pragma unroll
        for (int e = 0; e < 4; ++e) {
            float s = cout[oo * 17 + pq * 4 + e] + bias;
            res[e] = s > 0.0f ? s : 0.1f * s;
        }
        *(float4*)&out[((size_t)(b * 64 + oo)) * NP + n0 + pq * 4] =
            make_float4(res[0], res[1], res[2], res[3]);
    }
}

extern "C" void kernel_launch(void* const* d_in, const int* in_sizes, int n_in,
                              void* d_out, int out_size, void* d_ws, size_t ws_size,
                              hipStream_t stream) {
    const float* xyz  = (const float*)d_in[0];
    const float* pts  = (const float*)d_in[1];
    const float* w0   = (const float*)d_in[2];
    const float* b0   = (const float*)d_in[3];
    const float* w1   = (const float*)d_in[4];
    const float* b1   = (const float*)d_in[5];
    const float* w2   = (const float*)d_in[6];
    const float* b2   = (const float*)d_in[7];
    const float* lw   = (const float*)d_in[8];
    const float* linb = (const float*)d_in[9];
    float* out = (float*)d_out;

    char* ws = (char*)d_ws;
    float4* xyzt  = (float4*)(ws + OFF_XYZT);
    int*    idx   = (int*)(ws + OFF_IDX);
    float*  ptst  = (float*)(ws + OFF_PTST);
    uint4*  bfrag = (uint4*)(ws + OFF_BFRAG);

    k_prep<<<672, 256, 0, stream>>>(xyz, pts, lw, xyzt, ptst, bfrag);
    k_knn<<<512, 512, 0, stream>>>(xyzt, idx);
    k_wagg<<<BN / 16, 256, 0, stream>>>(xyzt, idx, ptst, bfrag,
                                        w0, b0, w1, b1, w2, b2, linb, out);
    (void)in_sizes; (void)n_in; (void)out_size; (void)ws_size;
}